// Round 7
// baseline (2340.982 us; speedup 1.0000x reference)
//
#include <hip/hip_runtime.h>

// GRU encoder: B=64, T=512, F=64, H=256, D=64.
//   k1: xproj = x @ kernel + bias -> f16 in d_ws, dot2-based GEMM (unchanged).
//   k2: Round-7: M=16 batched MFMA scan. 4 blocks x 1024 threads; each block
//       owns 16 batches so the 16x16x32 MFMA M-dimension carries 16 REAL
//       batch rows (round 6 wasted 15/16 of FLOPs on zero rows and 1.68e7
//       LDS conflict-cycles on broadcast reads of zeros).
//       Wave w owns cols w*16..w*16+15 for all 3 gates: 3 n-tiles x 8
//       k-tiles = 24 MFMA/wave/step, B-frags = 96 regs (AGPR-resident).
//       h[16][256] f16 in LDS, 16B-granule XOR swizzle (granule ^= row):
//       A-reads and h-writes are <=2-way bank aliased (free).
//       D layout (m89-verified): lane l, reg r = (batch (l>>4)*4+r,
//       col w*16+(l&15)) -> gates computed by ALL lanes, no divergence,
//       x loads/out stores per (lane,reg), one barrier/step.

typedef _Float16 half2_t __attribute__((ext_vector_type(2)));
typedef _Float16 f16x4_t __attribute__((ext_vector_type(4)));
typedef _Float16 f16x8_t __attribute__((ext_vector_type(8)));
typedef float f32x4_t __attribute__((ext_vector_type(4)));

#define LOG2E 1.4426950408889634f

__device__ __forceinline__ float fast_sigmoid(float x) {
  float e = __builtin_amdgcn_exp2f(-x * LOG2E);
  return __builtin_amdgcn_rcpf(1.0f + e);
}
__device__ __forceinline__ float fast_tanh(float x) {
  float e = __builtin_amdgcn_exp2f(x * (2.0f * LOG2E));
  return 1.0f - 2.0f * __builtin_amdgcn_rcpf(1.0f + e);
}

// ---------------------------------------------------------------------------
// Kernel 1: xproj GEMM.  C(32768x768) = A(32768x64) @ B(64x768) + bias.
// (unchanged)
// ---------------------------------------------------------------------------
__global__ __launch_bounds__(256, 4) void xproj_gemm(
    const float* __restrict__ x, const float* __restrict__ kmat,
    const float* __restrict__ bias, _Float16* __restrict__ xp) {
  __shared__ half2_t As2[32][132];  // [kpair][row]
  __shared__ half2_t Bs2[32][132];  // [kpair][col]
  const int tid = threadIdx.x;
  const int rb = blockIdx.x * 128;
  const int cb = blockIdx.y * 128;

  {
    const int k4 = (tid & 15) * 4;
    const int r0 = tid >> 4;
#pragma unroll
    for (int p = 0; p < 8; ++p) {
      int r = r0 + p * 16;
      float4 v = *(const float4*)(x + (size_t)(rb + r) * 64 + k4);
      half2_t lo, hi;
      lo[0] = (_Float16)v.x; lo[1] = (_Float16)v.y;
      hi[0] = (_Float16)v.z; hi[1] = (_Float16)v.w;
      As2[k4 / 2][r] = lo;
      As2[k4 / 2 + 1][r] = hi;
    }
  }
  {
    const int c4 = (tid & 31) * 4;
    const int kp0 = tid >> 5;
#pragma unroll
    for (int p = 0; p < 4; ++p) {
      int kp = kp0 + p * 8;
      float4 va = *(const float4*)(kmat + (size_t)(2 * kp) * 768 + cb + c4);
      float4 vb = *(const float4*)(kmat + (size_t)(2 * kp + 1) * 768 + cb + c4);
      half2_t o0, o1, o2, o3;
      o0[0] = (_Float16)va.x; o0[1] = (_Float16)vb.x;
      o1[0] = (_Float16)va.y; o1[1] = (_Float16)vb.y;
      o2[0] = (_Float16)va.z; o2[1] = (_Float16)vb.z;
      o3[0] = (_Float16)va.w; o3[1] = (_Float16)vb.w;
      Bs2[kp][c4 + 0] = o0;
      Bs2[kp][c4 + 1] = o1;
      Bs2[kp][c4 + 2] = o2;
      Bs2[kp][c4 + 3] = o3;
    }
  }
  __syncthreads();

  const int tx = tid & 15, ty = tid >> 4;
  const int r0 = ty * 8;
  const int c0 = tx * 4;
  float acc[8][8];
  {
    float4 b0 = *(const float4*)(bias + cb + c0);
    float4 b1 = *(const float4*)(bias + cb + 64 + c0);
    float bz[8] = {b0.x, b0.y, b0.z, b0.w, b1.x, b1.y, b1.z, b1.w};
#pragma unroll
    for (int i = 0; i < 8; ++i)
#pragma unroll
      for (int j = 0; j < 8; ++j) acc[i][j] = bz[j];
  }

#pragma unroll 2
  for (int kp = 0; kp < 32; ++kp) {
    half2_t a2[8], b2[8];
    *(int4*)(&a2[0]) = *(const int4*)(&As2[kp][r0]);
    *(int4*)(&a2[4]) = *(const int4*)(&As2[kp][r0 + 4]);
    *(int2*)(&b2[0]) = *(const int2*)(&Bs2[kp][c0]);
    *(int2*)(&b2[2]) = *(const int2*)(&Bs2[kp][c0 + 2]);
    *(int2*)(&b2[4]) = *(const int2*)(&Bs2[kp][64 + c0]);
    *(int2*)(&b2[6]) = *(const int2*)(&Bs2[kp][64 + c0 + 2]);
#pragma unroll
    for (int i = 0; i < 8; ++i)
#pragma unroll
      for (int j = 0; j < 8; ++j)
        acc[i][j] = __builtin_amdgcn_fdot2(a2[i], b2[j], acc[i][j], false);
  }

#pragma unroll
  for (int i = 0; i < 8; ++i) {
    f16x4_t o0, o1;
#pragma unroll
    for (int j = 0; j < 4; ++j) {
      o0[j] = (_Float16)acc[i][j];
      o1[j] = (_Float16)acc[i][4 + j];
    }
    _Float16* dst = xp + (size_t)(rb + r0 + i) * 768 + cb;
    *(f16x4_t*)(dst + c0) = o0;
    *(f16x4_t*)(dst + 64 + c0) = o1;
  }
}

// ---------------------------------------------------------------------------
// Kernel 2: GRU scan, M=16 batched MFMA. 4 blocks x 1024 threads.
// Block bg: batches bg*16..bg*16+15. Wave w: cols w*16..+15 (each gate).
//   B-frag: wf[g][s][j] = W[k=s*32+(l>>4)*8+j][g*256+colw]   (96 regs)
//   A-frag: lane l reads h[batch=l&15][k=s*32+(l>>4)*8+j]    (same k-order)
//   D/C   : lane l reg r = (batch (l>>4)*4+r, colw)          [m89]
// h LDS: [16 rows][32 granules of 16B], physical granule = logical ^ row.
// One barrier/step, double-buffered (8 KB x2).
// ---------------------------------------------------------------------------
__global__ __launch_bounds__(1024, 4) void gru_scan(
    const _Float16* __restrict__ xp, const float* __restrict__ wr,
    const float* __restrict__ dw, const float* __restrict__ db,
    float* __restrict__ out, float* __restrict__ state) {
  __shared__ alignas(16) _Float16 hh[2 * 16 * 256];  // 16 KB double buffer
  __shared__ float hF[16 * 256];                     // final h (head input)

  const int tid = threadIdx.x;
  const int bg = blockIdx.x;      // batch group 0..3
  const int lane = tid & 63;
  const int w = tid >> 6;         // wave 0..15
  const int lq = lane >> 4;       // 0..3
  const int b15 = lane & 15;
  const int colw = w * 16 + b15;  // output column 0..255

  // --- W_rec B-fragments (AGPR-resident): k = s*32 + lq*8 + j.
  f16x8_t wf[3][8];
#pragma unroll
  for (int g = 0; g < 3; ++g)
#pragma unroll
    for (int s = 0; s < 8; ++s) {
      const float* wp = wr + (size_t)(s * 32 + lq * 8) * 768 + g * 256 + colw;
      f16x8_t v;
#pragma unroll
      for (int j = 0; j < 8; ++j) v[j] = (_Float16)wp[(size_t)j * 768];
      wf[g][s] = v;
    }

  // zero h(0) (buffer 0, 8 KB): 1024 threads x 8 B
  {
    int2 z2;
    z2.x = 0;
    z2.y = 0;
    ((int2*)hh)[tid] = z2;
  }

  // A-read byte addresses within a buffer: row b15, granule (s*4+lq)^b15.
  int a_addr[8];
#pragma unroll
  for (int s = 0; s < 8; ++s)
    a_addr[s] = b15 * 512 + (((s * 4 + lq) ^ b15) << 4);

  // h-write byte addresses per reg r: row br=lq*4+r, granule (colw>>3)^br.
  int w_addr[4];
  uint px[4], po[4];
#pragma unroll
  for (int r = 0; r < 4; ++r) {
    const int br = lq * 4 + r;
    w_addr[r] = br * 512 + (((colw >> 3) ^ br) << 4) + ((colw & 7) << 1);
    px[r] = ((uint)(bg * 16 + br) * (512u * 768u) + (uint)colw) * 2u;
    po[r] = ((uint)(bg * 16 + br) * (512u * 256u) + (uint)colw) * 4u;
  }
  const char* xpc = (const char*)xp;
  char* outc = (char*)out;

  float hp[4] = {0.0f, 0.0f, 0.0f, 0.0f};
  __syncthreads();

#define GSTEP(T, RD, WR)                                                    \
  {                                                                         \
    const uint xo = (uint)(T)*1536u;                                        \
    _Float16 xz[4], xr[4], xh[4];                                           \
    _Pragma("unroll") for (int r = 0; r < 4; ++r) {                         \
      const _Float16* xq = (const _Float16*)(xpc + (px[r] + xo));           \
      xz[r] = xq[0];                                                        \
      xr[r] = xq[256];                                                      \
      xh[r] = xq[512];                                                      \
    }                                                                       \
    f32x4_t az = {0.f, 0.f, 0.f, 0.f};                                      \
    f32x4_t ar = {0.f, 0.f, 0.f, 0.f};                                      \
    f32x4_t ah = {0.f, 0.f, 0.f, 0.f};                                      \
    _Pragma("unroll") for (int s = 0; s < 8; ++s) {                         \
      f16x8_t a = *(const f16x8_t*)((const char*)hh + (RD) + a_addr[s]);    \
      az = __builtin_amdgcn_mfma_f32_16x16x32_f16(a, wf[0][s], az, 0, 0, 0);\
      ar = __builtin_amdgcn_mfma_f32_16x16x32_f16(a, wf[1][s], ar, 0, 0, 0);\
      ah = __builtin_amdgcn_mfma_f32_16x16x32_f16(a, wf[2][s], ah, 0, 0, 0);\
    }                                                                       \
    _Pragma("unroll") for (int r = 0; r < 4; ++r) {                         \
      if ((T) > 0)                                                          \
        *(float*)(outc + (po[r] + ((uint)(T)-1u) * 1024u)) = hp[r];         \
      float z = fast_sigmoid((float)xz[r] + az[r]);                         \
      float rg = fast_sigmoid((float)xr[r] + ar[r]);                        \
      float hc = fast_tanh((float)xh[r] + rg * ah[r]);                      \
      hp[r] = hc + z * (hp[r] - hc);                                        \
      *(_Float16*)((char*)hh + (WR) + w_addr[r]) = (_Float16)hp[r];         \
    }                                                                       \
    __syncthreads();                                                        \
  }

#pragma unroll 1
  for (int tt = 0; tt < 512; tt += 2) {
    GSTEP(tt, 0, 8192)
    GSTEP(tt + 1, 8192, 0)
  }
#undef GSTEP

  // --- tail: out row 511 + stage h_last for the dense head
#pragma unroll
  for (int r = 0; r < 4; ++r) {
    *(float*)(outc + (po[r] + 511u * 1024u)) = hp[r];
    hF[(lq * 4 + r) * 256 + colw] = hp[r];
  }
  __syncthreads();

  // --- dense head: state[bg*16+bt,:] = tanh(h_last @ dense_w + dense_b)
  {
    const int bt = tid >> 6;  // batch 0..15
    const int d = lane;       // 0..63
    float acc = db[d];
#pragma unroll 8
    for (int k = 0; k < 256; ++k)
      acc = fmaf(hF[bt * 256 + k], dw[k * 64 + d], acc);
    state[(size_t)(bg * 16 + bt) * 64 + d] = fast_tanh(acc);
  }
}

// ---------------------------------------------------------------------------
extern "C" void kernel_launch(void* const* d_in, const int* in_sizes, int n_in,
                              void* d_out, int out_size, void* d_ws,
                              size_t ws_size, hipStream_t stream) {
  const float* x = (const float*)d_in[0];     // (64,512,64)
  const float* kmat = (const float*)d_in[1];  // (64,768)
  const float* wr = (const float*)d_in[2];    // (256,768)
  const float* bias = (const float*)d_in[3];  // (768,)
  const float* dw = (const float*)d_in[4];    // (256,64)
  const float* db = (const float*)d_in[5];    // (64,)

  float* out = (float*)d_out;                   // (64,512,256)
  float* state = out + (size_t)64 * 512 * 256;  // (64,64)
  _Float16* xp = (_Float16*)d_ws;               // 64*512*768 f16 = 48 MiB

  dim3 gg(32768 / 128, 768 / 128);
  xproj_gemm<<<gg, 256, 0, stream>>>(x, kmat, bias, xp);
  gru_scan<<<4, 1024, 0, stream>>>(xp, wr, dw, db, out, state);
}

// Round 8
// 2055.047 us; speedup vs baseline: 1.1391x; 1.1391x over previous
//
#include <hip/hip_runtime.h>

// GRU encoder: B=64, T=512, F=64, H=256, D=64.
//   k1: xproj = x @ kernel + bias -> f16 in d_ws, dot2-based GEMM (unchanged).
//   k2: Round-8: 16 blocks x 4 batches. W_rec fragment per thread UNCHANGED
//       (96 half2, shared across batches). Per step: 4x the proven 96-dot2
//       matvec (one per batch h), 12 part writes; gate phase now FULLY
//       PARALLEL (thread (kc,col) owns gate of (batch=kc, col)) so the
//       ~300cyc serial gate tail + ~880cyc/step idle (barrier drains, wave
//       skew) are paid once per 4 batches instead of per batch.
//       MFMA path abandoned: per-SIMD MFMA cost floor (~1860cyc/step) does
//       not beat dot2; 4-block variant added 5x latency exposure (R7).

typedef _Float16 half2_t __attribute__((ext_vector_type(2)));
typedef _Float16 f16x4_t __attribute__((ext_vector_type(4)));

#define LOG2E 1.4426950408889634f

__device__ __forceinline__ float fast_sigmoid(float x) {
  float e = __builtin_amdgcn_exp2f(-x * LOG2E);
  return __builtin_amdgcn_rcpf(1.0f + e);
}
__device__ __forceinline__ float fast_tanh(float x) {
  float e = __builtin_amdgcn_exp2f(x * (2.0f * LOG2E));
  return 1.0f - 2.0f * __builtin_amdgcn_rcpf(1.0f + e);
}

// ---------------------------------------------------------------------------
// Kernel 1: xproj GEMM.  C(32768x768) = A(32768x64) @ B(64x768) + bias.
// (unchanged)
// ---------------------------------------------------------------------------
__global__ __launch_bounds__(256, 4) void xproj_gemm(
    const float* __restrict__ x, const float* __restrict__ kmat,
    const float* __restrict__ bias, _Float16* __restrict__ xp) {
  __shared__ half2_t As2[32][132];  // [kpair][row]
  __shared__ half2_t Bs2[32][132];  // [kpair][col]
  const int tid = threadIdx.x;
  const int rb = blockIdx.x * 128;
  const int cb = blockIdx.y * 128;

  {
    const int k4 = (tid & 15) * 4;
    const int r0 = tid >> 4;
#pragma unroll
    for (int p = 0; p < 8; ++p) {
      int r = r0 + p * 16;
      float4 v = *(const float4*)(x + (size_t)(rb + r) * 64 + k4);
      half2_t lo, hi;
      lo[0] = (_Float16)v.x; lo[1] = (_Float16)v.y;
      hi[0] = (_Float16)v.z; hi[1] = (_Float16)v.w;
      As2[k4 / 2][r] = lo;
      As2[k4 / 2 + 1][r] = hi;
    }
  }
  {
    const int c4 = (tid & 31) * 4;
    const int kp0 = tid >> 5;
#pragma unroll
    for (int p = 0; p < 4; ++p) {
      int kp = kp0 + p * 8;
      float4 va = *(const float4*)(kmat + (size_t)(2 * kp) * 768 + cb + c4);
      float4 vb = *(const float4*)(kmat + (size_t)(2 * kp + 1) * 768 + cb + c4);
      half2_t o0, o1, o2, o3;
      o0[0] = (_Float16)va.x; o0[1] = (_Float16)vb.x;
      o1[0] = (_Float16)va.y; o1[1] = (_Float16)vb.y;
      o2[0] = (_Float16)va.z; o2[1] = (_Float16)vb.z;
      o3[0] = (_Float16)va.w; o3[1] = (_Float16)vb.w;
      Bs2[kp][c4 + 0] = o0;
      Bs2[kp][c4 + 1] = o1;
      Bs2[kp][c4 + 2] = o2;
      Bs2[kp][c4 + 3] = o3;
    }
  }
  __syncthreads();

  const int tx = tid & 15, ty = tid >> 4;
  const int r0 = ty * 8;
  const int c0 = tx * 4;
  float acc[8][8];
  {
    float4 b0 = *(const float4*)(bias + cb + c0);
    float4 b1 = *(const float4*)(bias + cb + 64 + c0);
    float bz[8] = {b0.x, b0.y, b0.z, b0.w, b1.x, b1.y, b1.z, b1.w};
#pragma unroll
    for (int i = 0; i < 8; ++i)
#pragma unroll
      for (int j = 0; j < 8; ++j) acc[i][j] = bz[j];
  }

#pragma unroll 2
  for (int kp = 0; kp < 32; ++kp) {
    half2_t a2[8], b2[8];
    *(int4*)(&a2[0]) = *(const int4*)(&As2[kp][r0]);
    *(int4*)(&a2[4]) = *(const int4*)(&As2[kp][r0 + 4]);
    *(int2*)(&b2[0]) = *(const int2*)(&Bs2[kp][c0]);
    *(int2*)(&b2[2]) = *(const int2*)(&Bs2[kp][c0 + 2]);
    *(int2*)(&b2[4]) = *(const int2*)(&Bs2[kp][64 + c0]);
    *(int2*)(&b2[6]) = *(const int2*)(&Bs2[kp][64 + c0 + 2]);
#pragma unroll
    for (int i = 0; i < 8; ++i)
#pragma unroll
      for (int j = 0; j < 8; ++j)
        acc[i][j] = __builtin_amdgcn_fdot2(a2[i], b2[j], acc[i][j], false);
  }

#pragma unroll
  for (int i = 0; i < 8; ++i) {
    f16x4_t o0, o1;
#pragma unroll
    for (int j = 0; j < 4; ++j) {
      o0[j] = (_Float16)acc[i][j];
      o1[j] = (_Float16)acc[i][4 + j];
    }
    _Float16* dst = xp + (size_t)(rb + r0 + i) * 768 + cb;
    *(f16x4_t*)(dst + c0) = o0;
    *(f16x4_t*)(dst + 64 + c0) = o1;
  }
}

// ---------------------------------------------------------------------------
// Kernel 2: GRU scan, 4 batches/block. 16 blocks x 1024 threads = 16 waves.
// Thread (kc = tid>>8, col = tid&255):
//   matvec: holds W_rec[k in 64kc..64kc+63][{col,col+256,col+512}] as 96
//           half2 (same as R0); computes partials for ALL 4 batches.
//   gates : owns (batch = kc, col) -> 1024 gates fully parallel.
// part[b]: row (gate*256+col), stride 6 floats, entry [kc]  (72 KB).
// h: hhalf[4][256] f16; x loads / out stores coalesced per (batch,col).
// ---------------------------------------------------------------------------
__global__ __launch_bounds__(1024, 4) void gru_scan(
    const _Float16* __restrict__ xp, const float* __restrict__ wr,
    const float* __restrict__ dw, const float* __restrict__ db,
    float* __restrict__ out, float* __restrict__ state) {
  __shared__ float pw[4 * 768 * 6];  // 72 KB: [b][row][6], row=gate*256+col
  __shared__ alignas(16) _Float16 hhalf[4][256];  // 2 KB
  __shared__ float hbuf[4][256];                  // 4 KB (head input)

  const int tid = threadIdx.x;
  const int bg = blockIdx.x;   // batch group 0..15 (batches bg*4..bg*4+3)
  const int kc = tid >> 8;     // k-chunk (matvec) AND batch (gates), 0..3
  const int col = tid & 255;   // output column

  // --- W_rec fragment (96 half2), identical layout to R0.
  half2_t w2[3][32];
#pragma unroll
  for (int q = 0; q < 3; ++q) {
    const float* wp = wr + (size_t)(kc * 64) * 768 + col + q * 256;
#pragma unroll
    for (int j = 0; j < 32; ++j) {
      float wa = wp[(size_t)(2 * j) * 768];
      float wb = wp[(size_t)(2 * j + 1) * 768];
      half2_t p;
      p[0] = (_Float16)wa;
      p[1] = (_Float16)wb;
      w2[q][j] = p;
    }
  }

  hhalf[kc][col] = (_Float16)0.0f;
  __syncthreads();

  // Per-thread gate-role pointers: batch = kc.
  const _Float16* xpb = xp + (size_t)(bg * 4 + kc) * 512 * 768;
  float* outb = out + (size_t)(bg * 4 + kc) * 512 * 256;
  float hprev = 0.0f;

#pragma unroll 1
  for (int t = 0; t < 512; ++t) {
    // Deferred h(t-1) store + x prefetch for this thread's (batch,col).
    // Issued at step top -> drained/consumed well after the matvec.
    _Float16 x0, x1, x2;
    {
      if (t) outb[(size_t)(t - 1) * 256 + col] = hprev;
      const _Float16* xq = xpb + (size_t)t * 768 + col;
      x0 = xq[0];
      x1 = xq[256];
      x2 = xq[512];
    }

    // Matvec for all 4 batches with the shared W fragment.
#pragma unroll
    for (int b = 0; b < 4; ++b) {
      const int4* hp = (const int4*)&hhalf[b][0] + kc * 8;
      float a0 = 0.0f, a1 = 0.0f, a2 = 0.0f;
#pragma unroll
      for (int g = 0; g < 8; ++g) {
        int4 hv = hp[g];  // wave-uniform broadcast
        half2_t p0 = __builtin_bit_cast(half2_t, hv.x);
        half2_t p1 = __builtin_bit_cast(half2_t, hv.y);
        half2_t p2 = __builtin_bit_cast(half2_t, hv.z);
        half2_t p3 = __builtin_bit_cast(half2_t, hv.w);
        a0 = __builtin_amdgcn_fdot2(p0, w2[0][g * 4 + 0], a0, false);
        a0 = __builtin_amdgcn_fdot2(p1, w2[0][g * 4 + 1], a0, false);
        a0 = __builtin_amdgcn_fdot2(p2, w2[0][g * 4 + 2], a0, false);
        a0 = __builtin_amdgcn_fdot2(p3, w2[0][g * 4 + 3], a0, false);
        a1 = __builtin_amdgcn_fdot2(p0, w2[1][g * 4 + 0], a1, false);
        a1 = __builtin_amdgcn_fdot2(p1, w2[1][g * 4 + 1], a1, false);
        a1 = __builtin_amdgcn_fdot2(p2, w2[1][g * 4 + 2], a1, false);
        a1 = __builtin_amdgcn_fdot2(p3, w2[1][g * 4 + 3], a1, false);
        a2 = __builtin_amdgcn_fdot2(p0, w2[2][g * 4 + 0], a2, false);
        a2 = __builtin_amdgcn_fdot2(p1, w2[2][g * 4 + 1], a2, false);
        a2 = __builtin_amdgcn_fdot2(p2, w2[2][g * 4 + 2], a2, false);
        a2 = __builtin_amdgcn_fdot2(p3, w2[2][g * 4 + 3], a2, false);
      }
      float* pb = pw + b * 4608;
      pb[(size_t)col * 6 + kc] = a0;
      pb[(size_t)(256 + col) * 6 + kc] = a1;
      pb[(size_t)(512 + col) * 6 + kc] = a2;
    }
    __syncthreads();

    // Gates: fully parallel, thread owns (batch=kc, col).
    {
      const float2* pb = (const float2*)(pw + kc * 4608);
      float2 z0 = pb[col * 3 + 0];
      float2 z1 = pb[col * 3 + 1];
      float2 r0 = pb[(256 + col) * 3 + 0];
      float2 r1 = pb[(256 + col) * 3 + 1];
      float2 h0 = pb[(512 + col) * 3 + 0];
      float2 h1 = pb[(512 + col) * 3 + 1];
      float rz = (z0.x + z0.y) + (z1.x + z1.y);
      float rr = (r0.x + r0.y) + (r1.x + r1.y);
      float rh = (h0.x + h0.y) + (h1.x + h1.y);
      float z = fast_sigmoid((float)x0 + rz);
      float r = fast_sigmoid((float)x1 + rr);
      float hh = fast_tanh((float)x2 + r * rh);
      float hnew = z * hprev + (1.0f - z) * hh;
      hprev = hnew;
      hhalf[kc][col] = (_Float16)hnew;
    }
    __syncthreads();
  }

  outb[(size_t)511 * 256 + col] = hprev;
  hbuf[kc][col] = hprev;
  __syncthreads();

  // --- dense head: state[bg*4+bt,:] = tanh(h_last @ dense_w + dense_b)
  if (tid < 256) {
    const int bt = tid >> 6;  // batch 0..3
    const int d = tid & 63;
    float acc = db[d];
#pragma unroll 8
    for (int k = 0; k < 256; ++k)
      acc = fmaf(hbuf[bt][k], dw[k * 64 + d], acc);
    state[(size_t)(bg * 4 + bt) * 64 + d] = fast_tanh(acc);
  }
}

// ---------------------------------------------------------------------------
extern "C" void kernel_launch(void* const* d_in, const int* in_sizes, int n_in,
                              void* d_out, int out_size, void* d_ws,
                              size_t ws_size, hipStream_t stream) {
  const float* x = (const float*)d_in[0];     // (64,512,64)
  const float* kmat = (const float*)d_in[1];  // (64,768)
  const float* wr = (const float*)d_in[2];    // (256,768)
  const float* bias = (const float*)d_in[3];  // (768,)
  const float* dw = (const float*)d_in[4];    // (256,64)
  const float* db = (const float*)d_in[5];    // (64,)

  float* out = (float*)d_out;                   // (64,512,256)
  float* state = out + (size_t)64 * 512 * 256;  // (64,64)
  _Float16* xp = (_Float16*)d_ws;               // 64*512*768 f16 = 48 MiB

  dim3 gg(32768 / 128, 768 / 128);
  xproj_gemm<<<gg, 256, 0, stream>>>(x, kmat, bias, xp);
  gru_scan<<<16, 1024, 0, stream>>>(xp, wr, dw, db, out, state);
}

// Round 9
// 654.540 us; speedup vs baseline: 3.5765x; 3.1397x over previous
//
#include <hip/hip_runtime.h>

// GRU encoder: B=64, T=512, F=64, H=256, D=64.
//   k1: Round-9: xproj = x @ kernel + bias as an MFMA GEMM (was ~75us of
//       VALU dot2; roofline ~10-20us). 256 thr/block, 128x128 tile, no LDS:
//       A-frags = contiguous global float4 pairs (f32->f16 cvt in regs),
//       B-frags = 8 lane-coalesced scalar reads (L2-hot), 32 MFMA/wave.
//       A/B share one k-bijection; D-layout per m89 (verified R6/R7).
//   k2: gru_scan FROZEN at the round-5 version (measured floor of this
//       structure: ~578us; four structural rewrites all regressed).

typedef _Float16 half2_t __attribute__((ext_vector_type(2)));
typedef _Float16 f16x4_t __attribute__((ext_vector_type(4)));
typedef _Float16 f16x8_t __attribute__((ext_vector_type(8)));
typedef float f32x4_t __attribute__((ext_vector_type(4)));

#define LOG2E 1.4426950408889634f

__device__ __forceinline__ float fast_sigmoid(float x) {
  float e = __builtin_amdgcn_exp2f(-x * LOG2E);
  return __builtin_amdgcn_rcpf(1.0f + e);
}
__device__ __forceinline__ float fast_tanh(float x) {
  float e = __builtin_amdgcn_exp2f(x * (2.0f * LOG2E));
  return 1.0f - 2.0f * __builtin_amdgcn_rcpf(1.0f + e);
}

// ---------------------------------------------------------------------------
// Kernel 1: xproj GEMM via MFMA. C(32768x768) = A(32768x64) @ B(64x768) + b.
// Grid (256, 6), block 256 = 4 waves. Wave w: rows rb+w*32..+31, cols
// cb..cb+127. Fragments (16x16x32 f16, k = kt*32 + (lane>>4)*8 + j):
//   A: x[rb + w*32 + mt*16 + (l&15)][k]          (2 float4 loads, cvt f16)
//   B: kmat[k][cb + nt*16 + (l&15)]              (8 scalar loads, coalesced)
//   D: row (l>>4)*4 + r, col l&15                (m89; verified R6/R7)
// ---------------------------------------------------------------------------
__global__ __launch_bounds__(256) void xproj_gemm(
    const float* __restrict__ x, const float* __restrict__ kmat,
    const float* __restrict__ bias, _Float16* __restrict__ xp) {
  const int tid = threadIdx.x;
  const int lane = tid & 63;
  const int w = tid >> 6;   // wave 0..3
  const int q = lane >> 4;  // k-subgroup 0..3
  const int r15 = lane & 15;
  const int rb = blockIdx.x * 128;
  const int cb = blockIdx.y * 128;

  // B-fragments: bf[nt][kt][j] = kmat[kt*32+q*8+j][cb+nt*16+r15].
  f16x8_t bf[8][2];
#pragma unroll
  for (int nt = 0; nt < 8; ++nt)
#pragma unroll
    for (int kt = 0; kt < 2; ++kt) {
      const float* bp =
          kmat + (size_t)(kt * 32 + q * 8) * 768 + cb + nt * 16 + r15;
      f16x8_t v;
#pragma unroll
      for (int j = 0; j < 8; ++j) v[j] = (_Float16)bp[(size_t)j * 768];
      bf[nt][kt] = v;
    }

  // A-fragments: af[mt][kt][j] = x[rb+w*32+mt*16+r15][kt*32+q*8+j].
  f16x8_t af[2][2];
#pragma unroll
  for (int mt = 0; mt < 2; ++mt)
#pragma unroll
    for (int kt = 0; kt < 2; ++kt) {
      const float* ap =
          x + (size_t)(rb + w * 32 + mt * 16 + r15) * 64 + kt * 32 + q * 8;
      float4 v0 = *(const float4*)(ap);
      float4 v1 = *(const float4*)(ap + 4);
      f16x8_t v;
      v[0] = (_Float16)v0.x; v[1] = (_Float16)v0.y;
      v[2] = (_Float16)v0.z; v[3] = (_Float16)v0.w;
      v[4] = (_Float16)v1.x; v[5] = (_Float16)v1.y;
      v[6] = (_Float16)v1.z; v[7] = (_Float16)v1.w;
      af[mt][kt] = v;
    }

  float bz[8];
#pragma unroll
  for (int nt = 0; nt < 8; ++nt) bz[nt] = bias[cb + nt * 16 + r15];

#pragma unroll
  for (int mt = 0; mt < 2; ++mt)
#pragma unroll
    for (int nt = 0; nt < 8; ++nt) {
      f32x4_t acc = {0.f, 0.f, 0.f, 0.f};
      acc = __builtin_amdgcn_mfma_f32_16x16x32_f16(af[mt][0], bf[nt][0], acc,
                                                   0, 0, 0);
      acc = __builtin_amdgcn_mfma_f32_16x16x32_f16(af[mt][1], bf[nt][1], acc,
                                                   0, 0, 0);
      // D: lane l reg r -> row rb+w*32+mt*16+q*4+r, col cb+nt*16+r15.
      _Float16* dp =
          xp + (size_t)(rb + w * 32 + mt * 16 + q * 4) * 768 + cb + nt * 16 +
          r15;
#pragma unroll
      for (int r = 0; r < 4; ++r)
        dp[(size_t)r * 768] = (_Float16)(acc[r] + bz[nt]);
    }
}

// ---------------------------------------------------------------------------
// Kernel 2: GRU scan (FROZEN round-5 version; measured 577-584us).
// One block per batch row. 1024 threads = 16 waves. Thread (c = tid>>8,
// col = tid&255) holds W_rec[k in 64c..64c+63] for columns {col, col+256,
// col+512} as 96 packed f16 pairs. Gates on waves 0-3 only.
// part2 layout: row (gate*256+col), stride 6 floats, entry [c].
// ---------------------------------------------------------------------------
__global__ __launch_bounds__(1024, 4) void gru_scan(
    const _Float16* __restrict__ xp, const float* __restrict__ wr,
    const float* __restrict__ dw, const float* __restrict__ db,
    float* __restrict__ out, float* __restrict__ state) {
  __shared__ float2 part2[768 * 3];  // [(gate*256+col)*3 + pair], 18.4 KB
  __shared__ float hbuf[256];
  __shared__ alignas(16) _Float16 hhalf[256];

  const int tid = threadIdx.x;
  const int b = blockIdx.x;
  const int c = tid >> 8;     // k-chunk 0..3
  const int col = tid & 255;  // output column within gate

  // --- load W_rec fragment as f16 pairs.
  half2_t w2[3][32];
#pragma unroll
  for (int q = 0; q < 3; ++q) {
    const float* wp = wr + (size_t)(c * 64) * 768 + col + q * 256;
#pragma unroll
    for (int j = 0; j < 32; ++j) {
      float wa = wp[(size_t)(2 * j) * 768];
      float wb = wp[(size_t)(2 * j + 1) * 768];
      half2_t p;
      p[0] = (_Float16)wa;
      p[1] = (_Float16)wb;
      w2[q][j] = p;
    }
  }
#pragma unroll
  for (int q = 0; q < 3; ++q)
#pragma unroll
    for (int j = 0; j < 32; ++j) asm volatile("" : "+v"(w2[q][j]));

  if (tid < 256) hhalf[tid] = (_Float16)0.0f;
  __syncthreads();

  const _Float16* xpb = xp + (size_t)b * 512 * 768;
  float* outb = out + (size_t)b * 512 * 256;
  const int4* hp2 = (const int4*)hhalf + c * 8;
  float* pw = (float*)part2;
  float hprev = 0.0f;

#pragma unroll 1
  for (int t = 0; t < 512; ++t) {
    // Gate waves only: deferred h(t-1) store + direct coalesced x loads.
    _Float16 x0 = (_Float16)0.0f, x1 = (_Float16)0.0f, x2 = (_Float16)0.0f;
    if (tid < 256) {
      if (t) outb[(size_t)(t - 1) * 256 + tid] = hprev;
      const _Float16* xr = xpb + (size_t)t * 768 + tid;
      x0 = xr[0];
      x1 = xr[256];
      x2 = xr[512];
    }

    float a0 = 0.0f, a1 = 0.0f, a2 = 0.0f;
#pragma unroll
    for (int g = 0; g < 8; ++g) {
      int4 hv = hp2[g];  // wave-uniform broadcast read
      half2_t p0 = __builtin_bit_cast(half2_t, hv.x);
      half2_t p1 = __builtin_bit_cast(half2_t, hv.y);
      half2_t p2 = __builtin_bit_cast(half2_t, hv.z);
      half2_t p3 = __builtin_bit_cast(half2_t, hv.w);
      a0 = __builtin_amdgcn_fdot2(p0, w2[0][g * 4 + 0], a0, false);
      a0 = __builtin_amdgcn_fdot2(p1, w2[0][g * 4 + 1], a0, false);
      a0 = __builtin_amdgcn_fdot2(p2, w2[0][g * 4 + 2], a0, false);
      a0 = __builtin_amdgcn_fdot2(p3, w2[0][g * 4 + 3], a0, false);
      a1 = __builtin_amdgcn_fdot2(p0, w2[1][g * 4 + 0], a1, false);
      a1 = __builtin_amdgcn_fdot2(p1, w2[1][g * 4 + 1], a1, false);
      a1 = __builtin_amdgcn_fdot2(p2, w2[1][g * 4 + 2], a1, false);
      a1 = __builtin_amdgcn_fdot2(p3, w2[1][g * 4 + 3], a1, false);
      a2 = __builtin_amdgcn_fdot2(p0, w2[2][g * 4 + 0], a2, false);
      a2 = __builtin_amdgcn_fdot2(p1, w2[2][g * 4 + 1], a2, false);
      a2 = __builtin_amdgcn_fdot2(p2, w2[2][g * 4 + 2], a2, false);
      a2 = __builtin_amdgcn_fdot2(p3, w2[2][g * 4 + 3], a2, false);
    }
    // Transposed partials: row = gate*256+col, stride 6 floats, entry c.
    pw[col * 6 + c] = a0;
    pw[1536 + col * 6 + c] = a1;
    pw[3072 + col * 6 + c] = a2;
    __syncthreads();

    // --- gates: waves 0..3 only.
    if (tid < 256) {
      const int i = tid;
      float2 z0 = part2[i * 3 + 0];
      float2 z1 = part2[i * 3 + 1];
      float2 r0 = part2[768 + i * 3 + 0];
      float2 r1 = part2[768 + i * 3 + 1];
      float2 h0 = part2[1536 + i * 3 + 0];
      float2 h1 = part2[1536 + i * 3 + 1];
      float rz = (z0.x + z0.y) + (z1.x + z1.y);
      float rr = (r0.x + r0.y) + (r1.x + r1.y);
      float rh = (h0.x + h0.y) + (h1.x + h1.y);
      float z = fast_sigmoid((float)x0 + rz);
      float r = fast_sigmoid((float)x1 + rr);
      float hh = fast_tanh((float)x2 + r * rh);
      float hnew = z * hprev + (1.0f - z) * hh;
      hprev = hnew;
      hhalf[i] = (_Float16)hnew;
    }
    __syncthreads();
  }

  if (tid < 256) {
    outb[(size_t)511 * 256 + tid] = hprev;
    hbuf[tid] = hprev;
  }
  __syncthreads();

  // --- dense head: state[b,:] = tanh(h_last @ dense_w + dense_b)
  if (tid < 64) {
    float acc = db[tid];
#pragma unroll 8
    for (int k = 0; k < 256; ++k) acc = fmaf(hbuf[k], dw[k * 64 + tid], acc);
    state[(size_t)b * 64 + tid] = fast_tanh(acc);
  }
}

// ---------------------------------------------------------------------------
extern "C" void kernel_launch(void* const* d_in, const int* in_sizes, int n_in,
                              void* d_out, int out_size, void* d_ws,
                              size_t ws_size, hipStream_t stream) {
  const float* x = (const float*)d_in[0];     // (64,512,64)
  const float* kmat = (const float*)d_in[1];  // (64,768)
  const float* wr = (const float*)d_in[2];    // (256,768)
  const float* bias = (const float*)d_in[3];  // (768,)
  const float* dw = (const float*)d_in[4];    // (256,64)
  const float* db = (const float*)d_in[5];    // (64,)

  float* out = (float*)d_out;                   // (64,512,256)
  float* state = out + (size_t)64 * 512 * 256;  // (64,64)
  _Float16* xp = (_Float16*)d_ws;               // 64*512*768 f16 = 48 MiB

  dim3 gg(32768 / 128, 768 / 128);
  xproj_gemm<<<gg, 256, 0, stream>>>(x, kmat, bias, xp);
  gru_scan<<<64, 1024, 0, stream>>>(xp, wr, dw, db, out, state);
}